// Round 5
// baseline (167.690 us; speedup 1.0000x reference)
//
#include <hip/hip_runtime.h>
#include <cstdint>
#include <cstddef>

// ---------------------------------------------------------------------------
// DeMash = complex GEMM: out[bts, m] = sum_l y[bts, l] * conj(C)[m, l]
//   out_r = Yr@Cr^T + Yi@Ci^T ; out_i = Yi@Cr^T - Yr@Ci^T
// One real NT GEMM:
//   A [M=2048, K=3072] row-major fp16  (K: [Yr(1512) | Yi(1512) | 0-pad])
//   W [N=3072, K=3072] row-major fp16  (n<1512: [Cr|Ci|0]; 1512..3023:
//                                       [-Ci|Cr|0]; rest 0)
//   Out[m, n] = sum_k A[m,k] * W[n,k] -> scattered into [2,2048,14,128]
//
// R5: R4's cooperative launch failed (runtime co-residency bound from the
// reported 64KB/CU LDS -> max 512 blocks < 768; launch error, nothing ran).
// Revert to the proven 2-dispatch R3 structure. GEMM now explicitly
// double-buffered (48KB LDS, still 3 blocks/CU): loads for tile k+1 are
// issued right after the barrier and drained by the NEXT barrier, giving
// them the whole MFMA block of flight time (R3 drained vmcnt immediately,
// 54% stall at MfmaUtil 28%). Swizzle (conflicts=0) unchanged.
// ---------------------------------------------------------------------------

typedef _Float16 half_t;
typedef half_t half8 __attribute__((ext_vector_type(8)));
typedef float floatx4 __attribute__((ext_vector_type(4)));

#define M_DIM 2048
#define N_DIM 3072
#define K_DIM 3072
#define LDIM 1512
#define NSC 108
#define SYMS 14
#define FFT 128
#define ROWLEN (SYMS * FFT)   // 1792

#define BM 64
#define BN 128
#define BK 64
#define NITER (K_DIM / BK)    // 48

// prep grid partition (blocks of 256 threads)
#define PA_BLOCKS 3072   // A: 2048*3072/8/256, 8 halfs (16B) per thread
#define PW_BLOCKS 4608   // W: 3072*3072/8/256
#define PG_BLOCKS 4480   // guard zero: 2*2048*14*20/256

typedef __attribute__((address_space(3))) uint32_t lds_u32_t;
typedef const __attribute__((address_space(1))) uint32_t glob_u32_t;

__device__ __forceinline__ void gl2lds16(const void* g, void* l) {
    __builtin_amdgcn_global_load_lds((glob_u32_t*)g, (lds_u32_t*)l, 16, 0, 0);
}

// ---------------------------------------------------------------------------
// prep_all: one dispatch does A-build, W-build, guard zeroing (branch is
// wave-uniform on blockIdx). 1512 and 3024 are multiples of 8, so every
// 8-element chunk lies in a single source region.  (Unchanged from R3.)
// ---------------------------------------------------------------------------
__global__ __launch_bounds__(256) void prep_all(
    const float* __restrict__ xr, const float* __restrict__ xi,
    const float* __restrict__ Cr, const float* __restrict__ Ci,
    const int* __restrict__ sc,
    half_t* __restrict__ A, half_t* __restrict__ W, float* __restrict__ out)
{
    const int b = blockIdx.x;
    const int t = threadIdx.x;

    if (b < PA_BLOCKS) {
        int idx = b * 256 + t;                 // [0, 2048*384)
        int row = idx / 384;
        int k0 = (idx - row * 384) * 8;
        half_t v[8];
        const float* src = nullptr;
        int kb = k0;
        if (k0 < LDIM)            { src = xr; }
        else if (k0 < 2 * LDIM)   { src = xi; kb = k0 - LDIM; }
        if (src) {
            const float* rowp = src + (size_t)row * ROWLEN;
            int sym = kb / NSC;
            int j = kb - sym * NSC;
#pragma unroll
            for (int e = 0; e < 8; ++e) {
                v[e] = (half_t)rowp[sym * FFT + sc[j]];
                if (++j == NSC) { j = 0; ++sym; }
            }
        } else {
#pragma unroll
            for (int e = 0; e < 8; ++e) v[e] = (half_t)0.0f;
        }
        *(half8*)(A + (size_t)row * K_DIM + k0) = *(half8*)v;
    } else if (b < PA_BLOCKS + PW_BLOCKS) {
        int idx = (b - PA_BLOCKS) * 256 + t;   // [0, 3072*384)
        int n = idx / 384;
        int k0 = (idx - n * 384) * 8;
        half_t v[8];
        const float* src = nullptr;
        float sgn = 1.0f;
        int nn = n, kb = k0;
        if (n < LDIM) {
            if (k0 < LDIM)            { src = Cr; }
            else if (k0 < 2 * LDIM)   { src = Ci; kb = k0 - LDIM; }
        } else if (n < 2 * LDIM) {
            nn = n - LDIM;
            if (k0 < LDIM)            { src = Ci; sgn = -1.0f; }
            else if (k0 < 2 * LDIM)   { src = Cr; kb = k0 - LDIM; }
        }
        if (src) {
            const float* rowp = src + (size_t)nn * LDIM + kb;
#pragma unroll
            for (int e = 0; e < 8; ++e) v[e] = (half_t)(sgn * rowp[e]);
        } else {
#pragma unroll
            for (int e = 0; e < 8; ++e) v[e] = (half_t)0.0f;
        }
        *(half8*)(W + (size_t)n * K_DIM + k0) = *(half8*)v;
    } else {
        // zero guard columns [0,10) U [118,128) for all 4096 rows x 14 syms
        int idx = (b - PA_BLOCKS - PW_BLOCKS) * 256 + t;  // [0, 1146880)
        int c20 = idx % 20;
        int rest = idx / 20;
        int sym = rest % 14;
        int rowri = rest / 14;                 // [0, 4096) covers both ri
        int col = (c20 < 10) ? c20 : (NSC + c20);
        out[(size_t)rowri * ROWLEN + sym * FFT + col] = 0.0f;
    }
}

// ---------------------------------------------------------------------------
// gemm_scatter: 64x128 tile, BK=64, double-buffered LDS (2x24KB = 48KB,
// 3 blocks/CU). 4 waves, each 64Mx32N via 4x2 mfma_f32_16x16x32_f16 x 2
// k-steps. grid (24*32) = 768 blocks. XOR bank swizzle (conflicts = 0).
// K-loop: barrier -> issue loads for kb+1 into other buffer -> compute kb;
// next barrier drains the in-flight loads => within-wave overlap.
// ---------------------------------------------------------------------------
__global__ __launch_bounds__(256) void gemm_scatter(
    const half_t* __restrict__ A,   // [M_DIM][K_DIM]
    const half_t* __restrict__ W,   // [N_DIM][K_DIM]
    const int* __restrict__ sc,
    float* __restrict__ out)        // [2][2048][14][128]; guards pre-zeroed
{
    __shared__ __align__(16) half_t As[2][BM * BK];   // 2 x 8 KB
    __shared__ __align__(16) half_t Bs[2][BN * BK];   // 2 x 16 KB

    const int t = threadIdx.x;
    const int bn = blockIdx.x;
    const int bm = blockIdx.y;
    const int lane = t & 63;
    const int wn = (t >> 6) * 32;     // wave's N offset in tile

    floatx4 acc[4][2] = {};

    // ---- staging setup: chunk c (16B): row = c>>3, slot = c&7,
    //      global k-chunk g = slot ^ (row&7). LDS dest offset = c*8 halfs.
    const half_t* gAp[2];
    const half_t* gBp[4];
    int ofsA[2], ofsB[4];
#pragma unroll
    for (int r = 0; r < 2; ++r) {
        int c = r * 256 + t;
        int row = c >> 3, slot = c & 7;
        int g = slot ^ (row & 7);
        gAp[r] = A + (size_t)(bm * BM + row) * K_DIM + g * 8;
        ofsA[r] = c * 8;
    }
#pragma unroll
    for (int r = 0; r < 4; ++r) {
        int c = r * 256 + t;
        int row = c >> 3, slot = c & 7;
        int g = slot ^ (row & 7);
        gBp[r] = W + (size_t)(bn * BN + row) * K_DIM + g * 8;
        ofsB[r] = c * 8;
    }

    const int fr = lane & 15;         // fragment row (M or N within 16)
    const int cr = lane >> 4;         // k-quad index within a 32-k step
    const int slot0 = (cr) ^ (fr & 7);
    const int slot1 = (4 + cr) ^ (fr & 7);

    // prologue: fill buffer 0
    gl2lds16(gAp[0], &As[0][ofsA[0]]);
    gl2lds16(gAp[1], &As[0][ofsA[1]]);
    gl2lds16(gBp[0], &Bs[0][ofsB[0]]);
    gl2lds16(gBp[1], &Bs[0][ofsB[1]]);
    gl2lds16(gBp[2], &Bs[0][ofsB[2]]);
    gl2lds16(gBp[3], &Bs[0][ofsB[3]]);
    gAp[0] += BK; gAp[1] += BK;
    gBp[0] += BK; gBp[1] += BK; gBp[2] += BK; gBp[3] += BK;

    for (int kb = 0; kb < NITER; ++kb) {
        const int cur = kb & 1;
        __syncthreads();   // drains my in-flight loads into buf[cur]
        if (kb + 1 < NITER) {
            const int nxt = cur ^ 1;
            gl2lds16(gAp[0], &As[nxt][ofsA[0]]);
            gl2lds16(gAp[1], &As[nxt][ofsA[1]]);
            gl2lds16(gBp[0], &Bs[nxt][ofsB[0]]);
            gl2lds16(gBp[1], &Bs[nxt][ofsB[1]]);
            gl2lds16(gBp[2], &Bs[nxt][ofsB[2]]);
            gl2lds16(gBp[3], &Bs[nxt][ofsB[3]]);
            gAp[0] += BK; gAp[1] += BK;
            gBp[0] += BK; gBp[1] += BK; gBp[2] += BK; gBp[3] += BK;
        }

        half8 af[2][4], bf[2][2];
#pragma unroll
        for (int i = 0; i < 4; ++i) {
            int rbase = (i * 16 + fr) * BK;
            af[0][i] = *(const half8*)&As[cur][rbase + slot0 * 8];
            af[1][i] = *(const half8*)&As[cur][rbase + slot1 * 8];
        }
#pragma unroll
        for (int j = 0; j < 2; ++j) {
            int rbase = (wn + j * 16 + fr) * BK;
            bf[0][j] = *(const half8*)&Bs[cur][rbase + slot0 * 8];
            bf[1][j] = *(const half8*)&Bs[cur][rbase + slot1 * 8];
        }
#pragma unroll
        for (int s = 0; s < 2; ++s)
#pragma unroll
            for (int i = 0; i < 4; ++i)
#pragma unroll
                for (int j = 0; j < 2; ++j)
                    acc[i][j] = __builtin_amdgcn_mfma_f32_16x16x32_f16(
                        af[s][i], bf[s][j], acc[i][j], 0, 0, 0);
    }

    // epilogue: C/D layout col = lane&15 (N), row = (lane>>4)*4 + reg (M)
    const int col_base = bn * BN + wn + (lane & 15);
    const int row_base = bm * BM + ((lane >> 4) * 4);
#pragma unroll
    for (int j = 0; j < 2; ++j) {
        int n = col_base + j * 16;
        if (n >= 2 * LDIM) continue;           // N-pad region: discard
        int ri = (n >= LDIM) ? 1 : 0;
        int nn = n - ri * LDIM;
        int sym = nn / NSC;
        int jj = nn - sym * NSC;
        size_t colOff = (size_t)ri * (M_DIM * ROWLEN) + sym * FFT + sc[jj];
#pragma unroll
        for (int i = 0; i < 4; ++i) {
            int row0 = row_base + i * 16;
#pragma unroll
            for (int r = 0; r < 4; ++r) {
                out[colOff + (size_t)(row0 + r) * ROWLEN] = acc[i][j][r];
            }
        }
    }
}

// ---------------------------------------------------------------------------
extern "C" void kernel_launch(void* const* d_in, const int* in_sizes, int n_in,
                              void* d_out, int out_size, void* d_ws, size_t ws_size,
                              hipStream_t stream) {
    const float* xr = (const float*)d_in[0];
    const float* xi = (const float*)d_in[1];
    const float* Cr = (const float*)d_in[2];
    const float* Ci = (const float*)d_in[3];
    const int* sc   = (const int*)d_in[4];
    float* out = (float*)d_out;

    half_t* Ah = (half_t*)d_ws;                                      // 12.58 MB
    half_t* Wh = (half_t*)((char*)d_ws + (size_t)M_DIM * K_DIM * 2); // 18.87 MB

    prep_all<<<PA_BLOCKS + PW_BLOCKS + PG_BLOCKS, 256, 0, stream>>>(
        xr, xi, Cr, Ci, sc, Ah, Wh, out);

    dim3 grid(N_DIM / BN, M_DIM / BM);   // (24, 32) = 768 blocks
    gemm_scatter<<<grid, 256, 0, stream>>>(Ah, Wh, sc, out);
}

// Round 6
// 162.740 us; speedup vs baseline: 1.0304x; 1.0304x over previous
//
#include <hip/hip_runtime.h>
#include <cstdint>
#include <cstddef>

// ---------------------------------------------------------------------------
// DeMash = complex GEMM: out[bts, m] = sum_l y[bts, l] * conj(C)[m, l]
//   out_r = Yr@Cr^T + Yi@Ci^T ; out_i = Yi@Cr^T - Yr@Ci^T
// One real NT GEMM:
//   A [M=2048, K=3072] row-major fp16  (K: [Yr(1512) | Yi(1512) | 0-pad])
//   W [N=3072, K=3072] row-major fp16  (n<1512: [Cr|Ci|0]; 1512..3023:
//                                       [-Ci|Cr|0]; rest 0)
//   Out[m, n] = sum_k A[m,k] * W[n,k] -> scattered into [2,2048,14,128]
//
// R6: R5's 1-barrier dbuf regressed (57->69.6us; VALUBusy 18->29 for the
// dbuf bookkeeping, barrier vmcnt(0) drain unchanged) -- reverted to the
// 2-barrier single-buffer loop. This round: 128x128 tile (measured sweet
// spot, m103) with the two R3 fixes it never had: XOR swizzle (conflicts 0)
// + BK=64 (48 barriers). 32 MFMA / 8 staged chunks per wave-iter = 1.5x
// R3's compute intensity; grid 384 = 1.5 blocks/CU (R1 sustained 505 TF
// here even with 8-way conflicts on every read).
// ---------------------------------------------------------------------------

typedef _Float16 half_t;
typedef half_t half8 __attribute__((ext_vector_type(8)));
typedef float floatx4 __attribute__((ext_vector_type(4)));

#define M_DIM 2048
#define N_DIM 3072
#define K_DIM 3072
#define LDIM 1512
#define NSC 108
#define SYMS 14
#define FFT 128
#define ROWLEN (SYMS * FFT)   // 1792

#define BM 128
#define BN 128
#define BK 64
#define NITER (K_DIM / BK)    // 48

// prep grid partition (blocks of 256 threads)
#define PA_BLOCKS 3072   // A: 2048*3072/8/256, 8 halfs (16B) per thread
#define PW_BLOCKS 4608   // W: 3072*3072/8/256
#define PG_BLOCKS 4480   // guard zero: 2*2048*14*20/256

typedef __attribute__((address_space(3))) uint32_t lds_u32_t;
typedef const __attribute__((address_space(1))) uint32_t glob_u32_t;

__device__ __forceinline__ void gl2lds16(const void* g, void* l) {
    __builtin_amdgcn_global_load_lds((glob_u32_t*)g, (lds_u32_t*)l, 16, 0, 0);
}

// ---------------------------------------------------------------------------
// prep_all: one dispatch does A-build, W-build, guard zeroing (branch is
// wave-uniform on blockIdx). 1512 and 3024 are multiples of 8, so every
// 8-element chunk lies in a single source region.  (Unchanged, proven.)
// ---------------------------------------------------------------------------
__global__ __launch_bounds__(256) void prep_all(
    const float* __restrict__ xr, const float* __restrict__ xi,
    const float* __restrict__ Cr, const float* __restrict__ Ci,
    const int* __restrict__ sc,
    half_t* __restrict__ A, half_t* __restrict__ W, float* __restrict__ out)
{
    const int b = blockIdx.x;
    const int t = threadIdx.x;

    if (b < PA_BLOCKS) {
        int idx = b * 256 + t;                 // [0, 2048*384)
        int row = idx / 384;
        int k0 = (idx - row * 384) * 8;
        half_t v[8];
        const float* src = nullptr;
        int kb = k0;
        if (k0 < LDIM)            { src = xr; }
        else if (k0 < 2 * LDIM)   { src = xi; kb = k0 - LDIM; }
        if (src) {
            const float* rowp = src + (size_t)row * ROWLEN;
            int sym = kb / NSC;
            int j = kb - sym * NSC;
#pragma unroll
            for (int e = 0; e < 8; ++e) {
                v[e] = (half_t)rowp[sym * FFT + sc[j]];
                if (++j == NSC) { j = 0; ++sym; }
            }
        } else {
#pragma unroll
            for (int e = 0; e < 8; ++e) v[e] = (half_t)0.0f;
        }
        *(half8*)(A + (size_t)row * K_DIM + k0) = *(half8*)v;
    } else if (b < PA_BLOCKS + PW_BLOCKS) {
        int idx = (b - PA_BLOCKS) * 256 + t;   // [0, 3072*384)
        int n = idx / 384;
        int k0 = (idx - n * 384) * 8;
        half_t v[8];
        const float* src = nullptr;
        float sgn = 1.0f;
        int nn = n, kb = k0;
        if (n < LDIM) {
            if (k0 < LDIM)            { src = Cr; }
            else if (k0 < 2 * LDIM)   { src = Ci; kb = k0 - LDIM; }
        } else if (n < 2 * LDIM) {
            nn = n - LDIM;
            if (k0 < LDIM)            { src = Ci; sgn = -1.0f; }
            else if (k0 < 2 * LDIM)   { src = Cr; kb = k0 - LDIM; }
        }
        if (src) {
            const float* rowp = src + (size_t)nn * LDIM + kb;
#pragma unroll
            for (int e = 0; e < 8; ++e) v[e] = (half_t)(sgn * rowp[e]);
        } else {
#pragma unroll
            for (int e = 0; e < 8; ++e) v[e] = (half_t)0.0f;
        }
        *(half8*)(W + (size_t)n * K_DIM + k0) = *(half8*)v;
    } else {
        // zero guard columns [0,10) U [118,128) for all 4096 rows x 14 syms
        int idx = (b - PA_BLOCKS - PW_BLOCKS) * 256 + t;  // [0, 1146880)
        int c20 = idx % 20;
        int rest = idx / 20;
        int sym = rest % 14;
        int rowri = rest / 14;                 // [0, 4096) covers both ri
        int col = (c20 < 10) ? c20 : (NSC + c20);
        out[(size_t)rowri * ROWLEN + sym * FFT + col] = 0.0f;
    }
}

// ---------------------------------------------------------------------------
// gemm_scatter: 128x128 tile, BK=64, single-buffered (32 KB LDS), 4 waves
// in 2x2, each wave 64Mx64N via 4x4 mfma_f32_16x16x32_f16 x 2 k-steps.
// grid (24, 16) = 384 blocks. XOR bank swizzle (conflicts = 0).
// ---------------------------------------------------------------------------
__global__ __launch_bounds__(256) void gemm_scatter(
    const half_t* __restrict__ A,   // [M_DIM][K_DIM]
    const half_t* __restrict__ W,   // [N_DIM][K_DIM]
    const int* __restrict__ sc,
    float* __restrict__ out)        // [2][2048][14][128]; guards pre-zeroed
{
    __shared__ __align__(16) half_t As[BM * BK];   // 16 KB
    __shared__ __align__(16) half_t Bs[BN * BK];   // 16 KB

    const int t = threadIdx.x;
    const int bn = blockIdx.x;
    const int bm = blockIdx.y;
    const int lane = t & 63;
    const int wave = t >> 6;
    const int wm = (wave & 1) * 64;   // wave's M offset in tile
    const int wn = (wave >> 1) * 64;  // wave's N offset in tile

    floatx4 acc[4][4] = {};

    // ---- staging setup: chunk c (16B): row = c>>3, slot = c&7,
    //      global k-chunk g = slot ^ (row&7). LDS dest offset = c*8 halfs.
    const half_t* gAp[4];
    const half_t* gBp[4];
    half_t* lAp[4];
    half_t* lBp[4];
#pragma unroll
    for (int r = 0; r < 4; ++r) {
        int c = r * 256 + t;
        int row = c >> 3, slot = c & 7;
        int g = slot ^ (row & 7);
        gAp[r] = A + (size_t)(bm * BM + row) * K_DIM + g * 8;
        lAp[r] = As + c * 8;
        gBp[r] = W + (size_t)(bn * BN + row) * K_DIM + g * 8;
        lBp[r] = Bs + c * 8;
    }

    const int fr = lane & 15;         // fragment row (M or N within 16)
    const int cr = lane >> 4;         // k-quad index within a 32-k step
    const int slot0 = (cr) ^ (fr & 7);
    const int slot1 = (4 + cr) ^ (fr & 7);

    for (int kb = 0; kb < NITER; ++kb) {
        __syncthreads();
#pragma unroll
        for (int r = 0; r < 4; ++r) {
            gl2lds16(gAp[r], lAp[r]);
            gl2lds16(gBp[r], lBp[r]);
            gAp[r] += BK;
            gBp[r] += BK;
        }
        __syncthreads();

        half8 af[2][4], bf[2][4];
#pragma unroll
        for (int i = 0; i < 4; ++i) {
            int rbase = (wm + i * 16 + fr) * BK;
            af[0][i] = *(const half8*)&As[rbase + slot0 * 8];
            af[1][i] = *(const half8*)&As[rbase + slot1 * 8];
        }
#pragma unroll
        for (int j = 0; j < 4; ++j) {
            int rbase = (wn + j * 16 + fr) * BK;
            bf[0][j] = *(const half8*)&Bs[rbase + slot0 * 8];
            bf[1][j] = *(const half8*)&Bs[rbase + slot1 * 8];
        }
#pragma unroll
        for (int s = 0; s < 2; ++s)
#pragma unroll
            for (int i = 0; i < 4; ++i)
#pragma unroll
                for (int j = 0; j < 4; ++j)
                    acc[i][j] = __builtin_amdgcn_mfma_f32_16x16x32_f16(
                        af[s][i], bf[s][j], acc[i][j], 0, 0, 0);
    }

    // epilogue: C/D layout col = lane&15 (N), row = (lane>>4)*4 + reg (M)
    const int col_base = bn * BN + wn + (lane & 15);
    const int row_base = bm * BM + wm + ((lane >> 4) * 4);
#pragma unroll
    for (int j = 0; j < 4; ++j) {
        int n = col_base + j * 16;
        if (n >= 2 * LDIM) continue;           // N-pad region: discard
        int ri = (n >= LDIM) ? 1 : 0;
        int nn = n - ri * LDIM;
        int sym = nn / NSC;
        int jj = nn - sym * NSC;
        size_t colOff = (size_t)ri * (M_DIM * ROWLEN) + sym * FFT + sc[jj];
#pragma unroll
        for (int i = 0; i < 4; ++i) {
            int row0 = row_base + i * 16;
#pragma unroll
            for (int r = 0; r < 4; ++r) {
                out[colOff + (size_t)(row0 + r) * ROWLEN] = acc[i][j][r];
            }
        }
    }
}

// ---------------------------------------------------------------------------
extern "C" void kernel_launch(void* const* d_in, const int* in_sizes, int n_in,
                              void* d_out, int out_size, void* d_ws, size_t ws_size,
                              hipStream_t stream) {
    const float* xr = (const float*)d_in[0];
    const float* xi = (const float*)d_in[1];
    const float* Cr = (const float*)d_in[2];
    const float* Ci = (const float*)d_in[3];
    const int* sc   = (const int*)d_in[4];
    float* out = (float*)d_out;

    half_t* Ah = (half_t*)d_ws;                                      // 12.58 MB
    half_t* Wh = (half_t*)((char*)d_ws + (size_t)M_DIM * K_DIM * 2); // 18.87 MB

    prep_all<<<PA_BLOCKS + PW_BLOCKS + PG_BLOCKS, 256, 0, stream>>>(
        xr, xi, Cr, Ci, sc, Ah, Wh, out);

    dim3 grid(N_DIM / BN, M_DIM / BM);   // (24, 16) = 384 blocks
    gemm_scatter<<<grid, 256, 0, stream>>>(Ah, Wh, sc, out);
}

// Round 7
// 153.260 us; speedup vs baseline: 1.0942x; 1.0619x over previous
//
#include <hip/hip_runtime.h>
#include <cstdint>
#include <cstddef>

// ---------------------------------------------------------------------------
// DeMash = complex GEMM: out[bts, m] = sum_l y[bts, l] * conj(C)[m, l]
//   out_r = Yr@Cr^T + Yi@Ci^T ; out_i = Yi@Cr^T - Yr@Ci^T
// One real NT GEMM:
//   A [M=2048, K=3072] row-major fp16  (K: [Yr(1512) | Yi(1512) | 0-pad])
//   W [N=3072, K=3072] row-major fp16  (n<1512: [Cr|Ci|0]; 1512..3023:
//                                       [-Ci|Cr|0]; rest 0)
//   Out[m, n] = sum_k A[m,k] * W[n,k] -> scattered into [2,2048,14,128]
//
// R7: GEMM reverted to R3's proven optimum (64x128, BK=64, swizzle,
// 2-barrier single-buffer; R5 dbuf and R6 128-tile both regressed).
// prep_all rewritten for coalescing: old version did 8 scalar loads/thread
// with lanes 128B apart (64 cache lines per load instr, ~55us). New layout:
// consecutive lanes -> consecutive addresses; W uses float4 loads; est ~15us.
// ---------------------------------------------------------------------------

typedef _Float16 half_t;
typedef half_t half8 __attribute__((ext_vector_type(8)));
typedef half_t half4 __attribute__((ext_vector_type(4)));
typedef half_t half2_t __attribute__((ext_vector_type(2)));
typedef float floatx4 __attribute__((ext_vector_type(4)));
typedef float floatv4 __attribute__((ext_vector_type(4)));

#define M_DIM 2048
#define N_DIM 3072
#define K_DIM 3072
#define LDIM 1512
#define NSC 108
#define SYMS 14
#define FFT 128
#define ROWLEN (SYMS * FFT)   // 1792

#define BM 64
#define BN 128
#define BK 64
#define NITER (K_DIM / BK)    // 48

// prep grid partition (blocks of 256 threads)
#define PA2_BLOCKS 6048   // A: 2048 rows x 14 syms x 54 j-pairs / 256
#define PW2_BLOCKS 9072   // W: 3072 rows x 756 k-quads / 256
#define PAP_BLOCKS 48     // A k-pad zero: 2048 x 48 halves / 8 / 256
#define PG_BLOCKS 4480    // guard zero: 2*2048*14*20 / 256
#define PREP_BLOCKS (PA2_BLOCKS + PW2_BLOCKS + PAP_BLOCKS + PG_BLOCKS)

typedef __attribute__((address_space(3))) uint32_t lds_u32_t;
typedef const __attribute__((address_space(1))) uint32_t glob_u32_t;

__device__ __forceinline__ void gl2lds16(const void* g, void* l) {
    __builtin_amdgcn_global_load_lds((glob_u32_t*)g, (lds_u32_t*)l, 16, 0, 0);
}

// ---------------------------------------------------------------------------
// prep_all (one dispatch, 4 regions, wave-uniform region branch):
//  [0, PA2): A-build. thread -> (row, sym, jp); lanes walk jp so loads of
//            xr/xi are 8B-stride coalesced, stores are contiguous half2.
//  [PA2, +PW2): W-build. thread -> (n, kq): one float4 load (contiguous
//            across lanes), half4 store. Rows >= 3024 write zeros.
//  then A k-pad zeros (cols 3024..3071), then output guard-column zeros.
// ---------------------------------------------------------------------------
__global__ __launch_bounds__(256) void prep_all(
    const float* __restrict__ xr, const float* __restrict__ xi,
    const float* __restrict__ Cr, const float* __restrict__ Ci,
    const int* __restrict__ sc,
    half_t* __restrict__ A, half_t* __restrict__ W, float* __restrict__ out)
{
    const int b = blockIdx.x;
    const int t = threadIdx.x;

    if (b < PA2_BLOCKS) {
        int idx = b * 256 + t;          // [0, 2048*14*54)
        int jp = idx % 54;
        int rest = idx / 54;
        int sym = rest % 14;
        int row = rest / 14;
        int s0 = sc[2 * jp];
        int s1 = sc[2 * jp + 1];
        const float* xrp = xr + (size_t)row * ROWLEN + sym * FFT;
        const float* xip = xi + (size_t)row * ROWLEN + sym * FFT;
        half2_t hr = { (half_t)xrp[s0], (half_t)xrp[s1] };
        half2_t hi = { (half_t)xip[s0], (half_t)xip[s1] };
        size_t dst = (size_t)row * K_DIM + sym * NSC + 2 * jp;
        *(half2_t*)(A + dst) = hr;
        *(half2_t*)(A + dst + LDIM) = hi;
    } else if (b < PA2_BLOCKS + PW2_BLOCKS) {
        int idx = (b - PA2_BLOCKS) * 256 + t;   // [0, 3072*756)
        int kq = idx % 756;
        int n = idx / 756;
        int k0 = kq * 4;
        floatv4 f = {0.0f, 0.0f, 0.0f, 0.0f};
        if (n < LDIM) {
            if (k0 < LDIM)
                f = *(const floatv4*)(Cr + (size_t)n * LDIM + k0);
            else
                f = *(const floatv4*)(Ci + (size_t)n * LDIM + (k0 - LDIM));
        } else if (n < 2 * LDIM) {
            int m = n - LDIM;
            if (k0 < LDIM) {
                f = *(const floatv4*)(Ci + (size_t)m * LDIM + k0);
                f = -f;
            } else {
                f = *(const floatv4*)(Cr + (size_t)m * LDIM + (k0 - LDIM));
            }
        }
        half4 h = { (half_t)f.x, (half_t)f.y, (half_t)f.z, (half_t)f.w };
        *(half4*)(W + (size_t)n * K_DIM + k0) = h;
    } else if (b < PA2_BLOCKS + PW2_BLOCKS + PAP_BLOCKS) {
        int idx = (b - PA2_BLOCKS - PW2_BLOCKS) * 256 + t;  // [0, 12288)
        int c = idx % 6;
        int row = idx / 6;
        half8 z = {};
        *(half8*)(A + (size_t)row * K_DIM + 2 * LDIM + c * 8) = z;
    } else {
        // zero guard columns [0,10) U [118,128) for all 4096 rows x 14 syms
        int idx = (b - PA2_BLOCKS - PW2_BLOCKS - PAP_BLOCKS) * 256 + t;
        int c20 = idx % 20;
        int rest = idx / 20;
        int sym = rest % 14;
        int rowri = rest / 14;                 // [0, 4096) covers both ri
        int col = (c20 < 10) ? c20 : (NSC + c20);
        out[(size_t)rowri * ROWLEN + sym * FFT + col] = 0.0f;
    }
}

// ---------------------------------------------------------------------------
// gemm_scatter: R3 verbatim. 64x128 tile, BK=64, single-buffered (24 KB),
// 4 waves each 64Mx32N via 4x2 mfma_f32_16x16x32_f16 x 2 k-steps.
// grid (24, 32) = 768 blocks = 3/CU. XOR bank swizzle (conflicts = 0).
// ---------------------------------------------------------------------------
__global__ __launch_bounds__(256) void gemm_scatter(
    const half_t* __restrict__ A,   // [M_DIM][K_DIM]
    const half_t* __restrict__ W,   // [N_DIM][K_DIM]
    const int* __restrict__ sc,
    float* __restrict__ out)        // [2][2048][14][128]; guards pre-zeroed
{
    __shared__ __align__(16) half_t As[BM * BK];   // 8 KB
    __shared__ __align__(16) half_t Bs[BN * BK];   // 16 KB

    const int t = threadIdx.x;
    const int bn = blockIdx.x;
    const int bm = blockIdx.y;
    const int lane = t & 63;
    const int wn = (t >> 6) * 32;     // wave's N offset in tile

    floatx4 acc[4][2] = {};

    // staging: chunk c (16B): row = c>>3, slot = c&7, global k-chunk
    // g = slot ^ (row&7). LDS dest = base + c*16 (contiguous per lane).
    const half_t* gAp[2];
    const half_t* gBp[4];
    half_t* lAp[2];
    half_t* lBp[4];
#pragma unroll
    for (int r = 0; r < 2; ++r) {
        int c = r * 256 + t;
        int row = c >> 3, slot = c & 7;
        int g = slot ^ (row & 7);
        gAp[r] = A + (size_t)(bm * BM + row) * K_DIM + g * 8;
        lAp[r] = As + c * 8;
    }
#pragma unroll
    for (int r = 0; r < 4; ++r) {
        int c = r * 256 + t;
        int row = c >> 3, slot = c & 7;
        int g = slot ^ (row & 7);
        gBp[r] = W + (size_t)(bn * BN + row) * K_DIM + g * 8;
        lBp[r] = Bs + c * 8;
    }

    const int fr = lane & 15;         // fragment row (M or N within 16)
    const int cr = lane >> 4;         // k-quad index within a 32-k step
    const int slot0 = (cr) ^ (fr & 7);
    const int slot1 = (4 + cr) ^ (fr & 7);

    for (int kb = 0; kb < NITER; ++kb) {
        __syncthreads();
        gl2lds16(gAp[0], lAp[0]);
        gl2lds16(gAp[1], lAp[1]);
        gl2lds16(gBp[0], lBp[0]);
        gl2lds16(gBp[1], lBp[1]);
        gl2lds16(gBp[2], lBp[2]);
        gl2lds16(gBp[3], lBp[3]);
        gAp[0] += BK; gAp[1] += BK;
        gBp[0] += BK; gBp[1] += BK; gBp[2] += BK; gBp[3] += BK;
        __syncthreads();

        half8 af[2][4], bf[2][2];
#pragma unroll
        for (int i = 0; i < 4; ++i) {
            int rbase = (i * 16 + fr) * BK;
            af[0][i] = *(const half8*)&As[rbase + slot0 * 8];
            af[1][i] = *(const half8*)&As[rbase + slot1 * 8];
        }
#pragma unroll
        for (int j = 0; j < 2; ++j) {
            int rbase = (wn + j * 16 + fr) * BK;
            bf[0][j] = *(const half8*)&Bs[rbase + slot0 * 8];
            bf[1][j] = *(const half8*)&Bs[rbase + slot1 * 8];
        }
#pragma unroll
        for (int s = 0; s < 2; ++s)
#pragma unroll
            for (int i = 0; i < 4; ++i)
#pragma unroll
                for (int j = 0; j < 2; ++j)
                    acc[i][j] = __builtin_amdgcn_mfma_f32_16x16x32_f16(
                        af[s][i], bf[s][j], acc[i][j], 0, 0, 0);
    }

    // epilogue: C/D layout col = lane&15 (N), row = (lane>>4)*4 + reg (M)
    const int col_base = bn * BN + wn + (lane & 15);
    const int row_base = bm * BM + ((lane >> 4) * 4);
#pragma unroll
    for (int j = 0; j < 2; ++j) {
        int n = col_base + j * 16;
        if (n >= 2 * LDIM) continue;           // N-pad region: discard
        int ri = (n >= LDIM) ? 1 : 0;
        int nn = n - ri * LDIM;
        int sym = nn / NSC;
        int jj = nn - sym * NSC;
        size_t colOff = (size_t)ri * (M_DIM * ROWLEN) + sym * FFT + sc[jj];
#pragma unroll
        for (int i = 0; i < 4; ++i) {
            int row0 = row_base + i * 16;
#pragma unroll
            for (int r = 0; r < 4; ++r) {
                out[colOff + (size_t)(row0 + r) * ROWLEN] = acc[i][j][r];
            }
        }
    }
}

// ---------------------------------------------------------------------------
extern "C" void kernel_launch(void* const* d_in, const int* in_sizes, int n_in,
                              void* d_out, int out_size, void* d_ws, size_t ws_size,
                              hipStream_t stream) {
    const float* xr = (const float*)d_in[0];
    const float* xi = (const float*)d_in[1];
    const float* Cr = (const float*)d_in[2];
    const float* Ci = (const float*)d_in[3];
    const int* sc   = (const int*)d_in[4];
    float* out = (float*)d_out;

    half_t* Ah = (half_t*)d_ws;                                      // 12.58 MB
    half_t* Wh = (half_t*)((char*)d_ws + (size_t)M_DIM * K_DIM * 2); // 18.87 MB

    prep_all<<<PREP_BLOCKS, 256, 0, stream>>>(
        xr, xi, Cr, Ci, sc, Ah, Wh, out);

    dim3 grid(N_DIM / BN, M_DIM / BM);   // (24, 32) = 768 blocks
    gemm_scatter<<<grid, 256, 0, stream>>>(Ah, Wh, sc, out);
}